// Round 2
// baseline (288.695 us; speedup 1.0000x reference)
//
#include <hip/hip_runtime.h>
#include <math.h>

#define NCLS 21
#define NCLS_OUT 20
#define NSORT 2048
#define SCORE_THRESH 0.05f
#define NMS_THRESH 0.3f

typedef unsigned long long u64;

// ---------------------------------------------------------------------------
// Workspace layout (fast path), total 11,305,040 bytes:
//   u64  M[20][2048][32]     10,485,760   suppression bitmask rows (j>i bits)
//   float sy1/sx1/sy2/sx2[20][2048]  4 x 163,840   sorted boxes (SoA)
//   int  order[20][2048]        163,840   sorted-pos -> original roi index
//   int  nvv[20]                     80   count of scores > SCORE_THRESH
// ---------------------------------------------------------------------------
#define MASK_BYTES   (20ull * NSORT * 32 * 8)
#define ARR_ELEMS    (20 * NSORT)
#define WS_NEEDED    (MASK_BYTES + 4ull * ARR_ELEMS * 4 + ARR_ELEMS * 4 + 80)

// Kernel 1: per-(roi, class) softmax + box decode, written directly into d_out
// in final (20, R, 5) layout [y1,x1,y2,x2,prob]. Also zeroes nvv[0..19].
// Float op order matches the reference exactly (absmax was 0.0 in R1).
__global__ __launch_bounds__(256) void decode_kernel(
    const float* __restrict__ loc, const float* __restrict__ scores,
    const float* __restrict__ rois, const int* __restrict__ ph,
    const int* __restrict__ pw, float* __restrict__ out, int R,
    int* __restrict__ nvv)
{
    int idx = blockIdx.x * blockDim.x + threadIdx.x;
    if (nvv && idx < NCLS_OUT) nvv[idx] = 0;
    int total = R * NCLS_OUT;
    if (idx >= total) return;
    int r = idx / NCLS_OUT;
    int c = idx - r * NCLS_OUT + 1;          // class 1..20
    float sh = (float)(*ph), sw = (float)(*pw);

    const float* srow = scores + r * NCLS;
    float m = -INFINITY;
#pragma unroll
    for (int k = 0; k < NCLS; ++k) m = fmaxf(m, srow[k]);
    float sum = 0.f, ec = 0.f;
#pragma unroll
    for (int k = 0; k < NCLS; ++k) {
        float e = expf(srow[k] - m);
        sum += e;
        if (k == c) ec = e;
    }

    float y1 = rois[r * 4 + 0], x1 = rois[r * 4 + 1];
    float y2 = rois[r * 4 + 2], x2 = rois[r * 4 + 3];
    float h = y2 - y1, w = x2 - x1;
    float cy = y1 + 0.5f * h, cx = x1 + 0.5f * w;

    float dy = loc[r * (NCLS * 4) + c * 4 + 0] * 0.1f;
    float dx = loc[r * (NCLS * 4) + c * 4 + 1] * 0.1f;
    float dh = loc[r * (NCLS * 4) + c * 4 + 2] * 0.2f;
    float dw = loc[r * (NCLS * 4) + c * 4 + 3] * 0.2f;
    float ncy = dy * h + cy;
    float ncx = dx * w + cx;
    float nh = expf(dh) * h;
    float nw = expf(dw) * w;
    float by1 = fminf(fmaxf(ncy - 0.5f * nh, 0.f), sh);
    float bx1 = fminf(fmaxf(ncx - 0.5f * nw, 0.f), sw);
    float by2 = fminf(fmaxf(ncy + 0.5f * nh, 0.f), sh);
    float bx2 = fminf(fmaxf(ncx + 0.5f * nw, 0.f), sw);

    float* o = out + ((size_t)(c - 1) * R + r) * 5;
    o[0] = by1; o[1] = bx1; o[2] = by2; o[3] = bx2;
    o[4] = ec / sum;
}

// Kernel 2: stable descending rank sort (== jnp.argsort(-scores)) by all-pairs
// comparison against LDS-broadcast scores. Writes sorted box SoA + order +
// atomically counts nvv (valid entries form a prefix under descending sort).
__global__ __launch_bounds__(256) void ranksort_kernel(
    const float* __restrict__ out, int R,
    float* __restrict__ sy1, float* __restrict__ sx1,
    float* __restrict__ sy2, float* __restrict__ sx2,
    int* __restrict__ order, int* __restrict__ nvv)
{
    __shared__ float sc[NSORT];
    int c = blockIdx.y;
    const float* slice = out + (size_t)c * R * 5;
    int tid = threadIdx.x;
    for (int k = tid; k < R; k += 256) sc[k] = slice[k * 5 + 4];
    __syncthreads();
    int i = blockIdx.x * 256 + tid;
    if (i >= R) return;
    float si = sc[i];
    int rank = 0;
    for (int j = 0; j < R; ++j) {
        float sj = sc[j];
        rank += (sj > si) || (sj == si && j < i);
    }
    int base = c * NSORT;
    sy1[base + rank] = slice[i * 5 + 0];
    sx1[base + rank] = slice[i * 5 + 1];
    sy2[base + rank] = slice[i * 5 + 2];
    sx2[base + rank] = slice[i * 5 + 3];
    order[base + rank] = i;
    if (si > SCORE_THRESH) atomicAdd(&nvv[c], 1);
}

// Kernel 3: suppression mask build. Thread per sorted row i: bits for j>i with
// IoU > NMS_THRESH, packed into u64 words [w0 .. nw). Words < w0 unwritten
// (reduce kernel never reads them).
__global__ __launch_bounds__(256) void mask_kernel(
    const float* __restrict__ sy1, const float* __restrict__ sx1,
    const float* __restrict__ sy2, const float* __restrict__ sx2,
    const int* __restrict__ nvv, u64* __restrict__ M)
{
    __shared__ float y1s[NSORT], x1s[NSORT], y2s[NSORT], x2s[NSORT];
    int c = blockIdx.y;
    int nv = nvv[c];
    int tid = threadIdx.x;
    int base = c * NSORT;
    for (int k = tid; k < nv; k += 256) {
        y1s[k] = sy1[base + k]; x1s[k] = sx1[base + k];
        y2s[k] = sy2[base + k]; x2s[k] = sx2[base + k];
    }
    __syncthreads();
    int i = blockIdx.x * 256 + tid;
    if (i >= nv) return;
    float iy1 = y1s[i], ix1 = x1s[i], iy2 = y2s[i], ix2 = x2s[i];
    float iarea = (iy2 - iy1) * (ix2 - ix1);
    int nw = (nv + 63) >> 6;
    int w0 = (i + 1) >> 6;
    u64* rowp = M + (((size_t)(c << 11) + i) << 5);
    for (int w = w0; w < nw; ++w) {
        u64 m = 0;
        int jlo = max(w * 64, i + 1);
        int jhi = min(w * 64 + 64, nv);
        for (int j = jlo; j < jhi; ++j) {
            float ty1 = fmaxf(iy1, y1s[j]);
            float tx1 = fmaxf(ix1, x1s[j]);
            float ty2 = fminf(iy2, y2s[j]);
            float tx2 = fminf(ix2, x2s[j]);
            float inter = fmaxf(ty2 - ty1, 0.f) * fmaxf(tx2 - tx1, 0.f);
            float jarea = (y2s[j] - y1s[j]) * (x2s[j] - x1s[j]);
            float uni = fmaxf(iarea + jarea - inter, 1e-10f);
            if (inter / uni > NMS_THRESH) m |= (1ull << (j & 63));
        }
        rowp[w] = m;
    }
}

// Kernel 4: wave-synchronous greedy reduction + output zeroing. One wave per
// class; `removed` words live in registers (lane l owns word l). Per 64-pivot
// word: lanes preload candidate row-words, resolve in-register via shfl
// broadcast (no barriers in the serial chain), then OR kept rows' later words
// with coalesced loads.
__global__ __launch_bounds__(64) void reduce_kernel(
    float* __restrict__ out, int R, const u64* __restrict__ M,
    const int* __restrict__ order, const int* __restrict__ nvv)
{
    __shared__ u64 rem[32];
    int c = blockIdx.x;
    int lane = threadIdx.x;
    int nv = nvv[c];
    int nw = (nv + 63) >> 6;
    u64 removed = 0;
    const u64* Mc = M + ((size_t)c << 16);   // c * 2048 * 32

    for (int w = 0; w < nw; ++w) {
        // lane l holds row-word M[w*64+l][w]; last bit of a word has no j>i
        // in-word (row word unwritten) -> force 0.
        int ic = w * 64 + lane;
        u64 cand = 0;
        if (ic < nv && lane != 63) cand = Mc[((size_t)ic << 5) + w];

        u64 cur = __shfl(removed, w, 64);    // removed word w (uniform)
        int remn = nv - w * 64;
        u64 vb = (remn >= 64) ? ~0ull : ((1ull << remn) - 1ull);
        u64 avail = vb & ~cur;
        u64 kept = 0;
        while (avail) {                      // uniform loop, register-only
            int b = __ffsll((u64)avail) - 1;
            kept |= (1ull << b);
            u64 rw = __shfl(cand, b, 64);    // broadcast pivot's in-word bits
            cur |= rw;
            avail &= ~(cur | (1ull << b));
        }
        if (lane == w) removed = cur;
        // deferred: OR kept pivots' later row-words (coalesced 256B rows)
        u64 km = kept;
        while (km) {
            int b = __ffsll((u64)km) - 1;
            km &= km - 1;
            int i = w * 64 + b;
            int wlo = (i + 1) >> 6;          // first written word of row i
            if (lane > w && lane < nw && lane >= wlo)
                removed |= Mc[((size_t)i << 5) + lane];
        }
    }
    if (lane < 32) rem[lane] = (lane < nw) ? removed : 0;
    __syncthreads();

    float* slice = out + (size_t)c * R * 5;
    const int* ord = order + c * NSORT;
    for (int i = lane; i < R; i += 64) {
        bool keep = (i < nv) && !((rem[i >> 6] >> (i & 63)) & 1ull);
        if (!keep) {
            float* p = slice + (size_t)ord[i] * 5;
            p[0] = 0.f; p[1] = 0.f; p[2] = 0.f; p[3] = 0.f; p[4] = 0.f;
        }
    }
}

// --------------------------- fallback path (R1) ----------------------------
// Used only if ws_size < WS_NEEDED. Known-correct, ~190 us.
__global__ __launch_bounds__(1024) void nms_kernel(float* __restrict__ out, int R)
{
    __shared__ u64 key[NSORT];
    __shared__ float by1s[NSORT], bx1s[NSORT];
    __shared__ float by2s[NSORT], bx2s[NSORT];
    __shared__ unsigned char removed[NSORT];
    __shared__ unsigned char keepf[NSORT];
    __shared__ int nvalid;

    int tid = threadIdx.x;
    int c = blockIdx.x;
    float* slice = out + (size_t)c * R * 5;

    for (int i = tid; i < NSORT; i += 1024) {
        u64 k;
        if (i < R) {
            unsigned sb = __float_as_uint(slice[i * 5 + 4]);
            k = ((u64)(~sb) << 32) | (unsigned)i;
        } else k = ~0ull;
        key[i] = k; removed[i] = 0; keepf[i] = 0;
    }
    if (tid == 0) nvalid = R;
    __syncthreads();

    for (unsigned kk = 2; kk <= NSORT; kk <<= 1) {
        for (unsigned j = kk >> 1; j > 0; j >>= 1) {
            for (unsigned i = tid; i < NSORT; i += 1024) {
                unsigned ixj = i ^ j;
                if (ixj > i) {
                    bool up = ((i & kk) == 0);
                    u64 a = key[i], b = key[ixj];
                    if ((a > b) == up) { key[i] = b; key[ixj] = a; }
                }
            }
            __syncthreads();
        }
    }

    for (int i = tid; i < R; i += 1024) {
        unsigned o = (unsigned)(key[i] & 0xffffffffu);
        by1s[i] = slice[o * 5 + 0]; bx1s[i] = slice[o * 5 + 1];
        by2s[i] = slice[o * 5 + 2]; bx2s[i] = slice[o * 5 + 3];
        float s = __uint_as_float(~(unsigned)(key[i] >> 32));
        if (!(s > SCORE_THRESH)) atomicMin(&nvalid, i);
    }
    __syncthreads();
    int nv = nvalid;

    for (int i = 0; i < nv; ++i) {
        if (removed[i]) continue;
        if (tid == 0) keepf[i] = 1;
        float iy1 = by1s[i], ix1 = bx1s[i], iy2 = by2s[i], ix2 = bx2s[i];
        float iarea = (iy2 - iy1) * (ix2 - ix1);
        for (int j = i + 1 + tid; j < nv; j += 1024) {
            if (!removed[j]) {
                float ty1 = fmaxf(iy1, by1s[j]);
                float tx1 = fmaxf(ix1, bx1s[j]);
                float ty2 = fminf(iy2, by2s[j]);
                float tx2 = fminf(ix2, bx2s[j]);
                float inter = fmaxf(ty2 - ty1, 0.f) * fmaxf(tx2 - tx1, 0.f);
                float jarea = (by2s[j] - by1s[j]) * (bx2s[j] - bx1s[j]);
                float uni = fmaxf(iarea + jarea - inter, 1e-10f);
                if (inter / uni > NMS_THRESH) removed[j] = 1;
            }
        }
        __syncthreads();
    }
    __syncthreads();

    for (int i = tid; i < R; i += 1024) {
        if (!keepf[i]) {
            unsigned o = (unsigned)(key[i] & 0xffffffffu);
            float* p = slice + (size_t)o * 5;
            p[0] = 0.f; p[1] = 0.f; p[2] = 0.f; p[3] = 0.f; p[4] = 0.f;
        }
    }
}

extern "C" void kernel_launch(void* const* d_in, const int* in_sizes, int n_in,
                              void* d_out, int out_size, void* d_ws, size_t ws_size,
                              hipStream_t stream) {
    const float* loc    = (const float*)d_in[0];   // (R, 84) f32
    const float* scores = (const float*)d_in[1];   // (R, 21) f32
    const float* rois   = (const float*)d_in[2];   // (R, 4)  f32
    const int*   ph     = (const int*)d_in[3];
    const int*   pw     = (const int*)d_in[4];
    float* out = (float*)d_out;                    // (20, R, 5) f32
    int R = in_sizes[2] / 4;
    int total = R * NCLS_OUT;

    if (ws_size >= WS_NEEDED && R <= NSORT) {
        char* wsb = (char*)d_ws;
        u64*   M    = (u64*)wsb;
        float* sy1  = (float*)(wsb + MASK_BYTES);
        float* sx1  = sy1 + ARR_ELEMS;
        float* sy2  = sx1 + ARR_ELEMS;
        float* sx2  = sy2 + ARR_ELEMS;
        int*   ordr = (int*)(sx2 + ARR_ELEMS);
        int*   nvv  = ordr + ARR_ELEMS;

        decode_kernel<<<(total + 255) / 256, 256, 0, stream>>>(
            loc, scores, rois, ph, pw, out, R, nvv);
        dim3 g((R + 255) / 256, NCLS_OUT);
        ranksort_kernel<<<g, 256, 0, stream>>>(out, R, sy1, sx1, sy2, sx2, ordr, nvv);
        mask_kernel<<<g, 256, 0, stream>>>(sy1, sx1, sy2, sx2, nvv, M);
        reduce_kernel<<<NCLS_OUT, 64, 0, stream>>>(out, R, M, ordr, nvv);
    } else {
        decode_kernel<<<(total + 255) / 256, 256, 0, stream>>>(
            loc, scores, rois, ph, pw, out, R, (int*)nullptr);
        nms_kernel<<<NCLS_OUT, 1024, 0, stream>>>(out, R);
    }
}

// Round 3
// 247.161 us; speedup vs baseline: 1.1680x; 1.1680x over previous
//
#include <hip/hip_runtime.h>
#include <math.h>

#define NCLS 21
#define NCLS_OUT 20
#define RMAX 2000            // fused-path capacity (R=2000 in this problem)
#define NTH 512
#define UNROLL_J ((RMAX + NTH - 1) / NTH)   // 4
#define SCORE_THRESH 0.05f
#define NMS_THRESH 0.3f

typedef unsigned long long u64;
typedef unsigned short u16;

// ---------------------------------------------------------------------------
// ONE kernel: block = one class (20 blocks x 512 threads).
// LDS (65,156 B <= 64 KB):
//   vkey  u64[2000]   16000 B   (~p_bits<<32 | roi_idx), in-place sorted
//   sy1..sx2 f32[2000] 32000 B  sorted valid boxes
//   chunk u64[64][33]  16896 B  per-chunk mask sub-block (stride 33 = no 2^k conflicts)
//   rem   u64[32]        256 B  removed bits per sorted word
// Float op order (softmax/decode/IoU-with-division) identical to R2 (absmax 0).
// ---------------------------------------------------------------------------
__global__ __launch_bounds__(NTH) void fused_kernel(
    const float* __restrict__ loc, const float* __restrict__ scores,
    const float* __restrict__ rois, const int* __restrict__ ph,
    const int* __restrict__ pw, float* __restrict__ out, int R)
{
    __shared__ u64 vkey[RMAX];
    __shared__ float sy1[RMAX], sx1[RMAX], sy2[RMAX], sx2[RMAX];
    __shared__ u64 chunk[64 * 33];
    __shared__ u64 rem[32];
    __shared__ int cnt;

    const int t = threadIdx.x;
    const int lane = t & 63;
    const int c = blockIdx.x + 1;              // class 1..20
    const float sh = (float)(*ph), sw = (float)(*pw);

    if (t == 0) cnt = 0;
    if (t < 32) rem[t] = 0;
    __syncthreads();

    // ---- Phase 0: softmax prob for class c; compact valid (unordered) ----
    for (int r = t; r < R; r += NTH) {
        const float* srow = scores + r * NCLS;
        float m = -INFINITY;
#pragma unroll
        for (int k = 0; k < NCLS; ++k) m = fmaxf(m, srow[k]);
        float sum = 0.f, ec = 0.f;
#pragma unroll
        for (int k = 0; k < NCLS; ++k) {
            float e = expf(srow[k] - m);
            sum += e;
            if (k == c) ec = e;
        }
        float p = ec / sum;
        if (p > SCORE_THRESH) {
            int j = atomicAdd(&cnt, 1);
            unsigned pb = __float_as_uint(p);
            vkey[j] = ((u64)(~pb) << 32) | (unsigned)r;
        }
    }
    __syncthreads();
    const int nv = cnt;
    const int nw = (nv + 63) >> 6;

    // ---- Phase 1: stable descending rank (== jnp.argsort(-p)) ----
    // key ascending u64 == p desc, idx asc (p >= 0 so ~bits reverses order).
    u64 kk[UNROLL_J];
    int rk[UNROLL_J];
#pragma unroll
    for (int u = 0; u < UNROLL_J; ++u) {
        int j = t + u * NTH;
        rk[u] = -1;
        if (j < nv) {
            u64 k = vkey[j];
            kk[u] = k;
            int rank = 0;
            for (int i = 0; i < nv; ++i) rank += (vkey[i] < k);
            rk[u] = rank;
        }
    }
    __syncthreads();                            // all ranking reads done

    // ---- Phase 2: decode valid boxes (exact ref op order), scatter sorted ----
#pragma unroll
    for (int u = 0; u < UNROLL_J; ++u) {
        if (rk[u] >= 0) {
            int r = (int)(kk[u] & 0xffffffffu);
            float4 rb = *(const float4*)(rois + r * 4);
            float y1 = rb.x, x1 = rb.y, y2 = rb.z, x2 = rb.w;
            float h = y2 - y1, w = x2 - x1;
            float cy = y1 + 0.5f * h, cx = x1 + 0.5f * w;
            float4 l4 = *(const float4*)(loc + r * (NCLS * 4) + c * 4);
            float dy = l4.x * 0.1f, dx = l4.y * 0.1f;
            float dh = l4.z * 0.2f, dw = l4.w * 0.2f;
            float ncy = dy * h + cy, ncx = dx * w + cx;
            float nh = expf(dh) * h, nwd = expf(dw) * w;
            float by1 = fminf(fmaxf(ncy - 0.5f * nh, 0.f), sh);
            float bx1 = fminf(fmaxf(ncx - 0.5f * nwd, 0.f), sw);
            float by2 = fminf(fmaxf(ncy + 0.5f * nh, 0.f), sh);
            float bx2 = fminf(fmaxf(ncx + 0.5f * nwd, 0.f), sw);
            int rank = rk[u];
            vkey[rank] = kk[u];
            sy1[rank] = by1; sx1[rank] = bx1;
            sy2[rank] = by2; sx2[rank] = bx2;
        }
    }
    __syncthreads();

    // ---- Phase 3: NMS, 64 pivots per chunk; mask sub-block lives in LDS ----
    for (int w = 0; w < nw; ++w) {
        int nwr = nw - w;
        u64 remw = rem[w];
        // 3a: compute chunk[il][vr] = suppression bits of pivot i=w*64+il over
        // word v=w+vr. Wave-uniform j (all lanes same v), pivot reads stride-1.
        for (int task = t; task < (nwr << 6); task += NTH) {
            int vr = task >> 6, il = task & 63;
            int i = (w << 6) + il;
            u64 m = 0;
            if (i < nv && !((remw >> il) & 1ull)) {
                float iy1 = sy1[i], ix1 = sx1[i], iy2 = sy2[i], ix2 = sx2[i];
                float iarea = (iy2 - iy1) * (ix2 - ix1);
                int v = w + vr;
                int j0 = v << 6;
                u64 rv = rem[v];                 // skip known-removed cols
                int jlo = (vr == 0) ? (il + 1) : 0;
                int jhi = min(64, nv - j0);
                for (int jj = jlo; jj < jhi; ++jj) {
                    if ((rv >> jj) & 1ull) continue;
                    int j = j0 + jj;
                    float ty1 = fmaxf(iy1, sy1[j]);
                    float tx1 = fmaxf(ix1, sx1[j]);
                    float ty2 = fminf(iy2, sy2[j]);
                    float tx2 = fminf(ix2, sx2[j]);
                    float inter = fmaxf(ty2 - ty1, 0.f) * fmaxf(tx2 - tx1, 0.f);
                    float jarea = (sy2[j] - sy1[j]) * (sx2[j] - sx1[j]);
                    float uni = fmaxf(iarea + jarea - inter, 1e-10f);
                    if (inter / uni > NMS_THRESH) m |= 1ull << jj;
                }
            }
            chunk[il * 33 + vr] = m;
        }
        __syncthreads();

        // 3b: in-word greedy resolution — register/shfl only, redundantly in
        // every wave (confluent from any rem[w] state between old and final,
        // so the t==0 store below cannot corrupt a late wave's result).
        u64 cand = chunk[lane * 33];
        u64 cur = rem[w];
        int remn = nv - (w << 6);
        u64 vb = (remn >= 64) ? ~0ull : ((1ull << remn) - 1ull);
        u64 avail = vb & ~cur;
        u64 kept = 0;
        while (avail) {
            int b = __ffsll(avail) - 1;
            kept |= 1ull << b;
            cur |= __shfl(cand, b, 64);
            avail &= ~(cur | (1ull << b));
        }

        // 3c: deferred ORs into later rem words — LDS reads, split over 16
        // pivot-groups x 32 words.
        int vr = t & 31, pg = t >> 5;
        if (vr >= 1 && vr < nwr) {
            u64 acc = 0, km = kept;
            int n = 0;
            while (km) {
                int b = __ffsll(km) - 1;
                km &= km - 1;
                if ((n & 15) == pg) acc |= chunk[b * 33 + vr];
                ++n;
            }
            if (acc) atomicOr(&rem[w + vr], acc);
        }
        if (t == 0) rem[w] = cur;
        __syncthreads();
    }

    // ---- Phase 4: inverse map (reuse chunk LDS) + single-pass output ----
    u16* inv = (u16*)chunk;
    for (int r = t; r < R; r += NTH) inv[r] = 0xffffu;
    __syncthreads();
    for (int i = t; i < nv; i += NTH) {
        if (!((rem[i >> 6] >> (i & 63)) & 1ull)) {
            int r = (int)(vkey[i] & 0xffffffffu);
            inv[r] = (u16)i;
        }
    }
    __syncthreads();
    float* slice = out + (size_t)(c - 1) * R * 5;
    for (int r = t; r < R; r += NTH) {
        int i = inv[r];
        float v0 = 0.f, v1 = 0.f, v2 = 0.f, v3 = 0.f, v4 = 0.f;
        if (i != 0xffff) {
            v0 = sy1[i]; v1 = sx1[i]; v2 = sy2[i]; v3 = sx2[i];
            v4 = __uint_as_float(~(unsigned)(vkey[i] >> 32));
        }
        float* p = slice + (size_t)r * 5;
        p[0] = v0; p[1] = v1; p[2] = v2; p[3] = v3; p[4] = v4;
    }
}

// --------------------------- fallback path (R1) ----------------------------
// Used only if R > RMAX. Known-correct (~258 us end-to-end).
__global__ __launch_bounds__(256) void decode_kernel(
    const float* __restrict__ loc, const float* __restrict__ scores,
    const float* __restrict__ rois, const int* __restrict__ ph,
    const int* __restrict__ pw, float* __restrict__ out, int R)
{
    int r = blockIdx.x * blockDim.x + threadIdx.x;
    if (r >= R) return;
    float sh = (float)(*ph), sw = (float)(*pw);
    float s[NCLS];
    float m = -INFINITY;
#pragma unroll
    for (int c = 0; c < NCLS; ++c) { s[c] = scores[r * NCLS + c]; m = fmaxf(m, s[c]); }
    float sum = 0.f;
#pragma unroll
    for (int c = 0; c < NCLS; ++c) { s[c] = expf(s[c] - m); sum += s[c]; }
    float y1 = rois[r * 4 + 0], x1 = rois[r * 4 + 1];
    float y2 = rois[r * 4 + 2], x2 = rois[r * 4 + 3];
    float h = y2 - y1, w = x2 - x1;
    float cy = y1 + 0.5f * h, cx = x1 + 0.5f * w;
    for (int c = 1; c < NCLS; ++c) {
        float dy = loc[r * (NCLS * 4) + c * 4 + 0] * 0.1f;
        float dx = loc[r * (NCLS * 4) + c * 4 + 1] * 0.1f;
        float dh = loc[r * (NCLS * 4) + c * 4 + 2] * 0.2f;
        float dw = loc[r * (NCLS * 4) + c * 4 + 3] * 0.2f;
        float ncy = dy * h + cy, ncx = dx * w + cx;
        float nh = expf(dh) * h, nw = expf(dw) * w;
        float by1 = fminf(fmaxf(ncy - 0.5f * nh, 0.f), sh);
        float bx1 = fminf(fmaxf(ncx - 0.5f * nw, 0.f), sw);
        float by2 = fminf(fmaxf(ncy + 0.5f * nh, 0.f), sh);
        float bx2 = fminf(fmaxf(ncx + 0.5f * nw, 0.f), sw);
        float* o = out + ((size_t)(c - 1) * R + r) * 5;
        o[0] = by1; o[1] = bx1; o[2] = by2; o[3] = bx2;
        o[4] = s[c] / sum;
    }
}

#define NSORT 2048
__global__ __launch_bounds__(1024) void nms_kernel(float* __restrict__ out, int R)
{
    __shared__ u64 key[NSORT];
    __shared__ float by1s[NSORT], bx1s[NSORT];
    __shared__ float by2s[NSORT], bx2s[NSORT];
    __shared__ unsigned char removed[NSORT];
    __shared__ unsigned char keepf[NSORT];
    __shared__ int nvalid;
    int tid = threadIdx.x;
    int c = blockIdx.x;
    float* slice = out + (size_t)c * R * 5;
    for (int i = tid; i < NSORT; i += 1024) {
        u64 k;
        if (i < R) {
            unsigned sb = __float_as_uint(slice[i * 5 + 4]);
            k = ((u64)(~sb) << 32) | (unsigned)i;
        } else k = ~0ull;
        key[i] = k; removed[i] = 0; keepf[i] = 0;
    }
    if (tid == 0) nvalid = R;
    __syncthreads();
    for (unsigned kkk = 2; kkk <= NSORT; kkk <<= 1) {
        for (unsigned j = kkk >> 1; j > 0; j >>= 1) {
            for (unsigned i = tid; i < NSORT; i += 1024) {
                unsigned ixj = i ^ j;
                if (ixj > i) {
                    bool up = ((i & kkk) == 0);
                    u64 a = key[i], b = key[ixj];
                    if ((a > b) == up) { key[i] = b; key[ixj] = a; }
                }
            }
            __syncthreads();
        }
    }
    for (int i = tid; i < R; i += 1024) {
        unsigned o = (unsigned)(key[i] & 0xffffffffu);
        by1s[i] = slice[o * 5 + 0]; bx1s[i] = slice[o * 5 + 1];
        by2s[i] = slice[o * 5 + 2]; bx2s[i] = slice[o * 5 + 3];
        float s = __uint_as_float(~(unsigned)(key[i] >> 32));
        if (!(s > SCORE_THRESH)) atomicMin(&nvalid, i);
    }
    __syncthreads();
    int nv = nvalid;
    for (int i = 0; i < nv; ++i) {
        if (removed[i]) continue;
        if (tid == 0) keepf[i] = 1;
        float iy1 = by1s[i], ix1 = bx1s[i], iy2 = by2s[i], ix2 = bx2s[i];
        float iarea = (iy2 - iy1) * (ix2 - ix1);
        for (int j = i + 1 + tid; j < nv; j += 1024) {
            if (!removed[j]) {
                float ty1 = fmaxf(iy1, by1s[j]);
                float tx1 = fmaxf(ix1, bx1s[j]);
                float ty2 = fminf(iy2, by2s[j]);
                float tx2 = fminf(ix2, bx2s[j]);
                float inter = fmaxf(ty2 - ty1, 0.f) * fmaxf(tx2 - tx1, 0.f);
                float jarea = (by2s[j] - by1s[j]) * (bx2s[j] - bx1s[j]);
                float uni = fmaxf(iarea + jarea - inter, 1e-10f);
                if (inter / uni > NMS_THRESH) removed[j] = 1;
            }
        }
        __syncthreads();
    }
    __syncthreads();
    for (int i = tid; i < R; i += 1024) {
        if (!keepf[i]) {
            unsigned o = (unsigned)(key[i] & 0xffffffffu);
            float* p = slice + (size_t)o * 5;
            p[0] = 0.f; p[1] = 0.f; p[2] = 0.f; p[3] = 0.f; p[4] = 0.f;
        }
    }
}

extern "C" void kernel_launch(void* const* d_in, const int* in_sizes, int n_in,
                              void* d_out, int out_size, void* d_ws, size_t ws_size,
                              hipStream_t stream) {
    const float* loc    = (const float*)d_in[0];   // (R, 84) f32
    const float* scores = (const float*)d_in[1];   // (R, 21) f32
    const float* rois   = (const float*)d_in[2];   // (R, 4)  f32
    const int*   ph     = (const int*)d_in[3];
    const int*   pw     = (const int*)d_in[4];
    float* out = (float*)d_out;                    // (20, R, 5) f32
    int R = in_sizes[2] / 4;

    if (R <= RMAX) {
        fused_kernel<<<NCLS_OUT, NTH, 0, stream>>>(loc, scores, rois, ph, pw, out, R);
    } else {
        decode_kernel<<<(R + 255) / 256, 256, 0, stream>>>(loc, scores, rois, ph, pw, out, R);
        nms_kernel<<<NCLS_OUT, 1024, 0, stream>>>(out, R);
    }
}

// Round 4
// 218.278 us; speedup vs baseline: 1.3226x; 1.1323x over previous
//
#include <hip/hip_runtime.h>
#include <math.h>

#define NCLS 21
#define NCLS_OUT 20
#define RMAX 2000            // fused-path capacity (R=2000 in this problem)
#define NTH 1024
#define SCORE_THRESH 0.05f

typedef unsigned long long u64;
typedef unsigned short u16;

// Exact equivalent of (f32_div(inter,uni) > 0.3f):  inter > IOU_MID * uni in f64.
// 0.3f = 10066330*2^-25, nextafterf up = 10066331*2^-25, midpoint = 20132661*2^-26.
// RN tie at midpoint rounds to even mantissa (0x19999A) = 0.3f -> "false", matching
// the strict "> midpoint" test. 25bit x 24bit product is exact in f64.
#define IOU_MID (20132661.0 / 67108864.0)

// ---------------------------------------------------------------------------
// ONE kernel: block = one class (20 blocks x 1024 threads).
// LDS (65,156 B):
//   vkey  u64[2000]      (~p_bits<<32 | roi_idx), in-place sorted
//   p1,p2 float2[2000]   sorted boxes (y1,x1),(y2,x2)
//   chunk u64[64*33]     per-chunk mask sub-block (stride 33)
//   rem   u64[32]        removed bits per sorted word
// ---------------------------------------------------------------------------
__global__ __launch_bounds__(NTH) void fused_kernel(
    const float* __restrict__ loc, const float* __restrict__ scores,
    const float* __restrict__ rois, const int* __restrict__ ph,
    const int* __restrict__ pw, float* __restrict__ out, int R)
{
    __shared__ u64 vkey[RMAX];
    __shared__ float2 p1[RMAX], p2[RMAX];
    __shared__ u64 chunk[64 * 33];
    __shared__ u64 rem[32];
    __shared__ int cnt;

    const int t = threadIdx.x;
    const int lane = t & 63;
    const int c = blockIdx.x + 1;              // class 1..20
    const float sh = (float)(*ph), sw = (float)(*pw);

    if (t == 0) cnt = 0;
    if (t < 32) rem[t] = 0;
    __syncthreads();

    // ---- Phase 0: softmax prob for class c; compact valid (unordered) ----
    for (int r = t; r < R; r += NTH) {
        const float* srow = scores + r * NCLS;
        float m = -INFINITY;
#pragma unroll
        for (int k = 0; k < NCLS; ++k) m = fmaxf(m, srow[k]);
        float sum = 0.f, ec = 0.f;
#pragma unroll
        for (int k = 0; k < NCLS; ++k) {
            float e = expf(srow[k] - m);
            sum += e;
            if (k == c) ec = e;
        }
        float p = ec / sum;
        if (p > SCORE_THRESH) {
            int j = atomicAdd(&cnt, 1);
            unsigned pb = __float_as_uint(p);
            vkey[j] = ((u64)(~pb) << 32) | (unsigned)r;
        }
    }
    __syncthreads();
    const int nv = cnt;
    const int nw = (nv + 63) >> 6;

    // ---- Phase 1: stable descending rank (== jnp.argsort(-p)), single pass ----
    u64 kk0 = 0, kk1 = 0;
    int r0 = 0, r1 = 0;
    bool in0 = (t < nv), in1 = (t + NTH < nv);
    if (in0) kk0 = vkey[t];
    if (in1) kk1 = vkey[t + NTH];
#pragma unroll 8
    for (int i = 0; i < nv; ++i) {
        u64 k = vkey[i];
        r0 += (k < kk0);
        r1 += (k < kk1);
    }
    __syncthreads();                            // all ranking reads done

    // ---- Phase 2: decode valid boxes (exact ref op order), scatter sorted ----
    for (int u = 0; u < 2; ++u) {
        bool act = u ? in1 : in0;
        if (act) {
            u64 kk = u ? kk1 : kk0;
            int rank = u ? r1 : r0;
            int r = (int)(kk & 0xffffffffu);
            float4 rb = *(const float4*)(rois + r * 4);
            float y1 = rb.x, x1 = rb.y, y2 = rb.z, x2 = rb.w;
            float h = y2 - y1, w = x2 - x1;
            float cy = y1 + 0.5f * h, cx = x1 + 0.5f * w;
            float4 l4 = *(const float4*)(loc + r * (NCLS * 4) + c * 4);
            float dy = l4.x * 0.1f, dx = l4.y * 0.1f;
            float dh = l4.z * 0.2f, dw = l4.w * 0.2f;
            float ncy = dy * h + cy, ncx = dx * w + cx;
            float nh = expf(dh) * h, nwd = expf(dw) * w;
            float by1 = fminf(fmaxf(ncy - 0.5f * nh, 0.f), sh);
            float bx1 = fminf(fmaxf(ncx - 0.5f * nwd, 0.f), sw);
            float by2 = fminf(fmaxf(ncy + 0.5f * nh, 0.f), sh);
            float bx2 = fminf(fmaxf(ncx + 0.5f * nwd, 0.f), sw);
            vkey[rank] = kk;
            p1[rank] = make_float2(by1, bx1);
            p2[rank] = make_float2(by2, bx2);
        }
    }
    __syncthreads();

    // ---- Phase 3: NMS, 64 pivots per chunk; mask sub-block lives in LDS ----
    for (int w = 0; w < nw; ++w) {
        int nwr = nw - w;
        u64 remw = rem[w];
        // 3a: chunk[il][vr] = suppression bits of pivot i=w*64+il over word
        // v=w+vr. Lanes share vr -> box reads of j are broadcast; pivot reads
        // are lane-stride-1. Branchless inner loop for pipelining; exact
        // division-free IoU compare.
        for (int task = t; task < (nwr << 6); task += NTH) {
            int vr = task >> 6, il = task & 63;
            int i = (w << 6) + il;
            u64 m = 0;
            if (i < nv && !((remw >> il) & 1ull)) {
                int v = w + vr;
                u64 rv = rem[v];                 // uniform per wave
                if (~rv != 0ull) {               // skip fully-removed words
                    float2 a1 = p1[i], a2 = p2[i];
                    float iarea = (a2.x - a1.x) * (a2.y - a1.y);
                    int j0 = v << 6;
                    int jhi = min(64, nv - j0);
#pragma unroll 4
                    for (int jj = 0; jj < jhi; ++jj) {
                        float2 b1 = p1[j0 + jj], b2 = p2[j0 + jj];
                        float ty1 = fmaxf(a1.x, b1.x);
                        float tx1 = fmaxf(a1.y, b1.y);
                        float ty2 = fminf(a2.x, b2.x);
                        float tx2 = fminf(a2.y, b2.y);
                        float inter = fmaxf(ty2 - ty1, 0.f) * fmaxf(tx2 - tx1, 0.f);
                        float jarea = (b2.x - b1.x) * (b2.y - b1.y);
                        float uni = fmaxf(iarea + jarea - inter, 1e-10f);
                        if ((double)inter > IOU_MID * (double)uni) m |= 1ull << jj;
                    }
                    if (vr == 0)                 // strict upper triangle only
                        m &= (il < 63) ? (~0ull << (il + 1)) : 0ull;
                }
            }
            chunk[il * 33 + vr] = m;
        }
        __syncthreads();

        // 3b: in-word greedy resolution — register/shfl only, redundantly in
        // every wave (confluent from any rem[w] state between old and final).
        u64 cand = chunk[lane * 33];
        u64 cur = rem[w];
        int remn = nv - (w << 6);
        u64 vb = (remn >= 64) ? ~0ull : ((1ull << remn) - 1ull);
        u64 avail = vb & ~cur;
        u64 kept = 0;
        while (avail) {
            int b = __ffsll(avail) - 1;
            kept |= 1ull << b;
            cur |= __shfl(cand, b, 64);
            avail &= ~(cur | (1ull << b));
        }

        // 3c: deferred ORs into later rem words — LDS reads, split over 32
        // pivot-groups x 32 words.
        int vr = t & 31, pg = t >> 5;
        if (vr >= 1 && vr < nwr) {
            u64 acc = 0, km = kept;
            int n = 0;
            while (km) {
                int b = __ffsll(km) - 1;
                km &= km - 1;
                if ((n & 31) == pg) acc |= chunk[b * 33 + vr];
                ++n;
            }
            if (acc) atomicOr(&rem[w + vr], acc);
        }
        if (t == 0) rem[w] = cur;
        __syncthreads();
    }

    // ---- Phase 4: inverse map (reuse chunk LDS) + single-pass output ----
    u16* inv = (u16*)chunk;
    for (int r = t; r < R; r += NTH) inv[r] = 0xffffu;
    __syncthreads();
    for (int i = t; i < nv; i += NTH) {
        if (!((rem[i >> 6] >> (i & 63)) & 1ull)) {
            int r = (int)(vkey[i] & 0xffffffffu);
            inv[r] = (u16)i;
        }
    }
    __syncthreads();
    float* slice = out + (size_t)(c - 1) * R * 5;
    for (int r = t; r < R; r += NTH) {
        int i = inv[r];
        float v0 = 0.f, v1 = 0.f, v2 = 0.f, v3 = 0.f, v4 = 0.f;
        if (i != 0xffff) {
            float2 a1 = p1[i], a2 = p2[i];
            v0 = a1.x; v1 = a1.y; v2 = a2.x; v3 = a2.y;
            v4 = __uint_as_float(~(unsigned)(vkey[i] >> 32));
        }
        float* p = slice + (size_t)r * 5;
        p[0] = v0; p[1] = v1; p[2] = v2; p[3] = v3; p[4] = v4;
    }
}

// --------------------------- fallback path (R1) ----------------------------
// Used only if R > RMAX. Known-correct.
__global__ __launch_bounds__(256) void decode_kernel(
    const float* __restrict__ loc, const float* __restrict__ scores,
    const float* __restrict__ rois, const int* __restrict__ ph,
    const int* __restrict__ pw, float* __restrict__ out, int R)
{
    int r = blockIdx.x * blockDim.x + threadIdx.x;
    if (r >= R) return;
    float sh = (float)(*ph), sw = (float)(*pw);
    float s[NCLS];
    float m = -INFINITY;
#pragma unroll
    for (int c = 0; c < NCLS; ++c) { s[c] = scores[r * NCLS + c]; m = fmaxf(m, s[c]); }
    float sum = 0.f;
#pragma unroll
    for (int c = 0; c < NCLS; ++c) { s[c] = expf(s[c] - m); sum += s[c]; }
    float y1 = rois[r * 4 + 0], x1 = rois[r * 4 + 1];
    float y2 = rois[r * 4 + 2], x2 = rois[r * 4 + 3];
    float h = y2 - y1, w = x2 - x1;
    float cy = y1 + 0.5f * h, cx = x1 + 0.5f * w;
    for (int c = 1; c < NCLS; ++c) {
        float dy = loc[r * (NCLS * 4) + c * 4 + 0] * 0.1f;
        float dx = loc[r * (NCLS * 4) + c * 4 + 1] * 0.1f;
        float dh = loc[r * (NCLS * 4) + c * 4 + 2] * 0.2f;
        float dw = loc[r * (NCLS * 4) + c * 4 + 3] * 0.2f;
        float ncy = dy * h + cy, ncx = dx * w + cx;
        float nh = expf(dh) * h, nw = expf(dw) * w;
        float by1 = fminf(fmaxf(ncy - 0.5f * nh, 0.f), sh);
        float bx1 = fminf(fmaxf(ncx - 0.5f * nw, 0.f), sw);
        float by2 = fminf(fmaxf(ncy + 0.5f * nh, 0.f), sh);
        float bx2 = fminf(fmaxf(ncx + 0.5f * nw, 0.f), sw);
        float* o = out + ((size_t)(c - 1) * R + r) * 5;
        o[0] = by1; o[1] = bx1; o[2] = by2; o[3] = bx2;
        o[4] = s[c] / sum;
    }
}

#define NSORT 2048
__global__ __launch_bounds__(1024) void nms_kernel(float* __restrict__ out, int R)
{
    __shared__ u64 key[NSORT];
    __shared__ float by1s[NSORT], bx1s[NSORT];
    __shared__ float by2s[NSORT], bx2s[NSORT];
    __shared__ unsigned char removed[NSORT];
    __shared__ unsigned char keepf[NSORT];
    __shared__ int nvalid;
    int tid = threadIdx.x;
    int c = blockIdx.x;
    float* slice = out + (size_t)c * R * 5;
    for (int i = tid; i < NSORT; i += 1024) {
        u64 k;
        if (i < R) {
            unsigned sb = __float_as_uint(slice[i * 5 + 4]);
            k = ((u64)(~sb) << 32) | (unsigned)i;
        } else k = ~0ull;
        key[i] = k; removed[i] = 0; keepf[i] = 0;
    }
    if (tid == 0) nvalid = R;
    __syncthreads();
    for (unsigned kkk = 2; kkk <= NSORT; kkk <<= 1) {
        for (unsigned j = kkk >> 1; j > 0; j >>= 1) {
            for (unsigned i = tid; i < NSORT; i += 1024) {
                unsigned ixj = i ^ j;
                if (ixj > i) {
                    bool up = ((i & kkk) == 0);
                    u64 a = key[i], b = key[ixj];
                    if ((a > b) == up) { key[i] = b; key[ixj] = a; }
                }
            }
            __syncthreads();
        }
    }
    for (int i = tid; i < R; i += 1024) {
        unsigned o = (unsigned)(key[i] & 0xffffffffu);
        by1s[i] = slice[o * 5 + 0]; bx1s[i] = slice[o * 5 + 1];
        by2s[i] = slice[o * 5 + 2]; bx2s[i] = slice[o * 5 + 3];
        float s = __uint_as_float(~(unsigned)(key[i] >> 32));
        if (!(s > SCORE_THRESH)) atomicMin(&nvalid, i);
    }
    __syncthreads();
    int nv = nvalid;
    for (int i = 0; i < nv; ++i) {
        if (removed[i]) continue;
        if (tid == 0) keepf[i] = 1;
        float iy1 = by1s[i], ix1 = bx1s[i], iy2 = by2s[i], ix2 = bx2s[i];
        float iarea = (iy2 - iy1) * (ix2 - ix1);
        for (int j = i + 1 + tid; j < nv; j += 1024) {
            if (!removed[j]) {
                float ty1 = fmaxf(iy1, by1s[j]);
                float tx1 = fmaxf(ix1, bx1s[j]);
                float ty2 = fminf(iy2, by2s[j]);
                float tx2 = fminf(ix2, bx2s[j]);
                float inter = fmaxf(ty2 - ty1, 0.f) * fmaxf(tx2 - tx1, 0.f);
                float jarea = (by2s[j] - by1s[j]) * (bx2s[j] - bx1s[j]);
                float uni = fmaxf(iarea + jarea - inter, 1e-10f);
                if (inter / uni > 0.3f) removed[j] = 1;
            }
        }
        __syncthreads();
    }
    __syncthreads();
    for (int i = tid; i < R; i += 1024) {
        if (!keepf[i]) {
            unsigned o = (unsigned)(key[i] & 0xffffffffu);
            float* p = slice + (size_t)o * 5;
            p[0] = 0.f; p[1] = 0.f; p[2] = 0.f; p[3] = 0.f; p[4] = 0.f;
        }
    }
}

extern "C" void kernel_launch(void* const* d_in, const int* in_sizes, int n_in,
                              void* d_out, int out_size, void* d_ws, size_t ws_size,
                              hipStream_t stream) {
    const float* loc    = (const float*)d_in[0];   // (R, 84) f32
    const float* scores = (const float*)d_in[1];   // (R, 21) f32
    const float* rois   = (const float*)d_in[2];   // (R, 4)  f32
    const int*   ph     = (const int*)d_in[3];
    const int*   pw     = (const int*)d_in[4];
    float* out = (float*)d_out;                    // (20, R, 5) f32
    int R = in_sizes[2] / 4;

    if (R <= RMAX) {
        fused_kernel<<<NCLS_OUT, NTH, 0, stream>>>(loc, scores, rois, ph, pw, out, R);
    } else {
        decode_kernel<<<(R + 255) / 256, 256, 0, stream>>>(loc, scores, rois, ph, pw, out, R);
        nms_kernel<<<NCLS_OUT, 1024, 0, stream>>>(out, R);
    }
}